// Round 5
// baseline (350.900 us; speedup 1.0000x reference)
//
#include <hip/hip_runtime.h>
#include <math.h>

#define N_ROWS 32768
#define DIM 256
#define K_CODES 1024

#define BM 64
#define BN 128
#define BK 64
#define LDX 68  // padded LDS stride in floats: 272B = 17*16B, float4-aligned, breaks bank collisions

// ---------------------------------------------------------------------------
// numpy-replica: pairwise sum of squares of a 128-float contiguous block,
// matching numpy's npyv AVX512 path (nlanes=16) at n=128:
//   8 vector "accumulators" = direct loads v_j[l] = e[16j+l],
//   lane-wise combine s[l] = ((v0+v1)+(v2+v3)) + ((v4+v5)+(v6+v7)),
//   then _mm512_reduce_add_ps fold tree:
//   T1[i]=s[i]+s[i+8]; T2[i]=T1[i]+T1[i+4]; res=(T2[0]+T2[2])+(T2[1]+T2[3]).
// Squares must be rounded BEFORE the adds (numpy computes x*x as a separate
// elementwise op) -> fp contract(off) to forbid fma fusion.
// ---------------------------------------------------------------------------
__device__ __forceinline__ float np_block128_sumsq(const float* e) {
#pragma clang fp contract(off)
    float s[16];
#pragma unroll
    for (int l = 0; l < 16; ++l) {
        float a0 = e[l]       * e[l];
        float a1 = e[16 + l]  * e[16 + l];
        float a2 = e[32 + l]  * e[32 + l];
        float a3 = e[48 + l]  * e[48 + l];
        float a4 = e[64 + l]  * e[64 + l];
        float a5 = e[80 + l]  * e[80 + l];
        float a6 = e[96 + l]  * e[96 + l];
        float a7 = e[112 + l] * e[112 + l];
        s[l] = ((a0 + a1) + (a2 + a3)) + ((a4 + a5) + (a6 + a7));
    }
    float t1[8];
#pragma unroll
    for (int i = 0; i < 8; ++i) t1[i] = s[i] + s[i + 8];
    float t2[4];
#pragma unroll
    for (int i = 0; i < 4; ++i) t2[i] = t1[i] + t1[i + 4];
    return (t2[0] + t2[2]) + (t2[1] + t2[3]);
}

// rows of 256 floats -> np-style sum of squares per row.
// n=256 pairwise split: pw(0..127) + pw(128..255).
__global__ __launch_bounds__(64) void npsumsq_kernel(const float* __restrict__ src,
                                                     float* __restrict__ dst) {
    __shared__ float buf[16][257];  // stride 257: threads 0..15 hit distinct banks
    const int tid = threadIdx.x;
    const int r0 = blockIdx.x * 16;
#pragma unroll
    for (int it = 0; it < 16; ++it) {
        int idx = it * 64 + tid;          // 0..1023 = 16 rows x 64 float4
        int r = idx >> 6, c4 = idx & 63;
        float4 v = ((const float4*)(src + (size_t)(r0 + r) * DIM))[c4];
        buf[r][c4 * 4 + 0] = v.x;
        buf[r][c4 * 4 + 1] = v.y;
        buf[r][c4 * 4 + 2] = v.z;
        buf[r][c4 * 4 + 3] = v.w;
    }
    __syncthreads();
    if (tid < 16) {
        const float* e = buf[tid];
        float b0 = np_block128_sumsq(e);
        float b1 = np_block128_sumsq(e + 128);
        dst[r0 + tid] = b0 + b1;  // split-combine add (no mul -> no fusion risk)
    }
}

// ---------------- tiled GEMM + np-f32-exact distances + argmin + gather ----------------
__global__ __launch_bounds__(256) void vq_kernel(
    const float* __restrict__ x, const float* __restrict__ w,
    const float* __restrict__ x2g, const float* __restrict__ w2g,
    float* __restrict__ zout, float* __restrict__ zq) {
    __shared__ float xs[BM * LDX];    // X tile [64][68]; reused for argmin reduce
    __shared__ float ws_[BN * LDX];   // W tile [128][68]
    __shared__ float sw2[K_CODES];
    __shared__ float sx2[BM];
    __shared__ int widx[BM];

    const int tid = threadIdx.x;
    const int bm0 = blockIdx.x * BM;
    const int rg = tid & 15;   // row group: rows rg + 16*i
    const int cg = tid >> 4;   // code group: codes cg + 16*j (within chunk)

    for (int i = tid; i < K_CODES; i += 256) sw2[i] = w2g[i];
    if (tid < BM) sx2[tid] = x2g[bm0 + tid];
    // (protected by the first __syncthreads inside the dk loop)

    float best[4];
    int bidx[4];
#pragma unroll
    for (int i = 0; i < 4; ++i) { best[i] = INFINITY; bidx[i] = 0; }

    const float4* x4 = (const float4*)x;
    const float4* w4 = (const float4*)w;

    for (int cn = 0; cn < K_CODES / BN; ++cn) {
        float acc[4][8];
#pragma unroll
        for (int i = 0; i < 4; ++i)
#pragma unroll
            for (int j = 0; j < 8; ++j) acc[i][j] = 0.f;

        for (int dk = 0; dk < DIM / BK; ++dk) {
            __syncthreads();  // previous compute done before overwriting tiles
            // stage X tile: 64 rows x 16 float4
#pragma unroll
            for (int p = 0; p < 4; ++p) {
                int l = p * 256 + tid;
                int row = l >> 4, c4 = l & 15;
                float4 v = x4[(size_t)(bm0 + row) * (DIM / 4) + dk * (BK / 4) + c4];
                *(float4*)&xs[row * LDX + c4 * 4] = v;
            }
            // stage W tile: 128 codes x 16 float4
#pragma unroll
            for (int p = 0; p < 8; ++p) {
                int l = p * 256 + tid;
                int row = l >> 4, c4 = l & 15;
                float4 v = w4[(size_t)(cn * BN + row) * (DIM / 4) + dk * (BK / 4) + c4];
                *(float4*)&ws_[row * LDX + c4 * 4] = v;
            }
            __syncthreads();
            // dot: strictly in-order k (dk asc, d asc, x->y->z->w), single acc, fma
            // == OpenBLAS sgemm microkernel accumulation semantics.
#pragma unroll
            for (int d = 0; d < BK; d += 4) {
                float4 xv[4], wv[8];
#pragma unroll
                for (int i = 0; i < 4; ++i)
                    xv[i] = *(const float4*)&xs[(rg + 16 * i) * LDX + d];
#pragma unroll
                for (int j = 0; j < 8; ++j)
                    wv[j] = *(const float4*)&ws_[(cg + 16 * j) * LDX + d];
#pragma unroll
                for (int i = 0; i < 4; ++i)
#pragma unroll
                    for (int j = 0; j < 8; ++j) {
                        acc[i][j] = __builtin_fmaf(xv[i].x, wv[j].x, acc[i][j]);
                        acc[i][j] = __builtin_fmaf(xv[i].y, wv[j].y, acc[i][j]);
                        acc[i][j] = __builtin_fmaf(xv[i].z, wv[j].z, acc[i][j]);
                        acc[i][j] = __builtin_fmaf(xv[i].w, wv[j].w, acc[i][j]);
                    }
            }
        }
        // fold: np expression rounding:  d = (x2 - 2*dot) + w2   (two roundings;
        // 2*dot is exact).  Ascending code order + strict < == np.argmin tie-break.
#pragma unroll
        for (int j = 0; j < 8; ++j) {
            int c = cn * BN + cg + 16 * j;
            float w2v = sw2[c];
#pragma unroll
            for (int i = 0; i < 4; ++i) {
                float t = sx2[rg + 16 * i] - 2.0f * acc[i][j];
                float s = t + w2v;
                if (s < best[i]) { best[i] = s; bidx[i] = c; }
            }
        }
    }

    __syncthreads();
    // cross-thread argmin reduce, reusing xs: sval [64][17], sidx [64][17]
    float* sval = xs;
    int* sidx = (int*)(xs + 64 * 17);
#pragma unroll
    for (int i = 0; i < 4; ++i) {
        sval[(rg + 16 * i) * 17 + cg] = best[i];
        sidx[(rg + 16 * i) * 17 + cg] = bidx[i];
    }
    __syncthreads();
    if (tid < BM) {
        float bv = INFINITY;
        int bi = 0;
        for (int c = 0; c < 16; ++c) {
            float v = sval[tid * 17 + c];
            int id = sidx[tid * 17 + c];
            if (v < bv || (v == bv && id < bi)) { bv = v; bi = id; }
        }
        widx[tid] = bi;
        zout[bm0 + tid] = (float)bi;  // index as float, exactly representable
    }
    __syncthreads();
    // gather z_q: 64 rows x 64 float4, coalesced
    float4* zq4 = (float4*)zq;
#pragma unroll
    for (int p = 0; p < 16; ++p) {
        int lin = p * 256 + tid;
        int row = lin >> 6, q = lin & 63;
        zq4[(size_t)(bm0 + row) * 64 + q] = w4[(size_t)widx[row] * 64 + q];
    }
}

extern "C" void kernel_launch(void* const* d_in, const int* in_sizes, int n_in,
                              void* d_out, int out_size, void* d_ws, size_t ws_size,
                              hipStream_t stream) {
    const float* z_e = (const float*)d_in[0];       // [32768][256]
    const float* emb = (const float*)d_in[1];       // [1024][256]
    float* x2g = (float*)d_ws;                      // [32768]
    float* w2g = x2g + N_ROWS;                      // [1024]
    float* zout = (float*)d_out;                    // [32768] indices as float
    float* zq = (float*)d_out + N_ROWS;             // [32768][256]

    npsumsq_kernel<<<N_ROWS / 16, 64, 0, stream>>>(z_e, x2g);
    npsumsq_kernel<<<K_CODES / 16, 64, 0, stream>>>(emb, w2g);
    vq_kernel<<<N_ROWS / BM, 256, 0, stream>>>(z_e, emb, x2g, w2g, zout, zq);
}

// Round 6
// 205.473 us; speedup vs baseline: 1.7078x; 1.7078x over previous
//
#include <hip/hip_runtime.h>
#include <math.h>

#define N_ROWS 32768
#define DIM 256
#define K_CODES 1024

// ---- ws layout (floats) ----
// x2:  [0, 32768)
// w2:  [32768, 33792)
// WT:  [33792, 33792 + 262144)   (256 x 1024, k-major)
#define WS_NEEDED ((size_t)(N_ROWS + K_CODES + DIM * K_CODES) * 4)

// ---------------------------------------------------------------------------
// numpy-replica pairwise sum of squares of a 128-float block (AVX512 path).
// ---------------------------------------------------------------------------
__device__ __forceinline__ float np_block128_sumsq(const float* e) {
#pragma clang fp contract(off)
    float s[16];
#pragma unroll
    for (int l = 0; l < 16; ++l) {
        float a0 = e[l]       * e[l];
        float a1 = e[16 + l]  * e[16 + l];
        float a2 = e[32 + l]  * e[32 + l];
        float a3 = e[48 + l]  * e[48 + l];
        float a4 = e[64 + l]  * e[64 + l];
        float a5 = e[80 + l]  * e[80 + l];
        float a6 = e[96 + l]  * e[96 + l];
        float a7 = e[112 + l] * e[112 + l];
        s[l] = ((a0 + a1) + (a2 + a3)) + ((a4 + a5) + (a6 + a7));
    }
    float t1[8];
#pragma unroll
    for (int i = 0; i < 8; ++i) t1[i] = s[i] + s[i + 8];
    float t2[4];
#pragma unroll
    for (int i = 0; i < 4; ++i) t2[i] = t1[i] + t1[i + 4];
    return (t2[0] + t2[2]) + (t2[1] + t2[3]);
}

__global__ __launch_bounds__(64) void npsumsq_kernel(const float* __restrict__ src,
                                                     float* __restrict__ dst) {
    __shared__ float buf[16][257];
    const int tid = threadIdx.x;
    const int r0 = blockIdx.x * 16;
#pragma unroll
    for (int it = 0; it < 16; ++it) {
        int idx = it * 64 + tid;
        int r = idx >> 6, c4 = idx & 63;
        float4 v = ((const float4*)(src + (size_t)(r0 + r) * DIM))[c4];
        buf[r][c4 * 4 + 0] = v.x;
        buf[r][c4 * 4 + 1] = v.y;
        buf[r][c4 * 4 + 2] = v.z;
        buf[r][c4 * 4 + 3] = v.w;
    }
    __syncthreads();
    if (tid < 16) {
        const float* e = buf[tid];
        dst[r0 + tid] = np_block128_sumsq(e) + np_block128_sumsq(e + 128);
    }
}

// ---------------------------------------------------------------------------
// W[1024][256] -> WT[256][1024]  (pure copy, no arithmetic)
// ---------------------------------------------------------------------------
__global__ __launch_bounds__(256) void transpose_kernel(const float* __restrict__ w,
                                                        float* __restrict__ wt) {
    __shared__ float t[64][68];
    const int tid = threadIdx.x;
    const int c0 = blockIdx.x * 64;  // code tile
    const int k0 = blockIdx.y * 64;  // k tile
#pragma unroll
    for (int i = 0; i < 4; ++i) {
        int l = i * 256 + tid;
        int r = l >> 4, q = l & 15;
        float4 v = *(const float4*)&w[(size_t)(c0 + r) * DIM + k0 + q * 4];
        t[r][q * 4 + 0] = v.x; t[r][q * 4 + 1] = v.y;
        t[r][q * 4 + 2] = v.z; t[r][q * 4 + 3] = v.w;
    }
    __syncthreads();
#pragma unroll
    for (int i = 0; i < 4; ++i) {
        int l = i * 256 + tid;
        int rk = l >> 4, q = l & 15;
        float4 v = make_float4(t[q * 4 + 0][rk], t[q * 4 + 1][rk],
                               t[q * 4 + 2][rk], t[q * 4 + 3][rk]);
        *(float4*)&wt[(size_t)(k0 + rk) * K_CODES + c0 + q * 4] = v;
    }
}

// ---------------------------------------------------------------------------
// Main: 16 rows x 1024 codes per block, 4 waves, lane owns 4 consecutive codes.
// No LDS in the k-loop: W from WT via coalesced float4 (L1/L2), X wave-uniform.
// FMA order per output: k = 0..255 strictly ascending, single accumulator ==
// OpenBLAS sgemm semantics (bitwise-verified in round 5).
// ---------------------------------------------------------------------------
__global__ __launch_bounds__(256) void vq_main(
    const float* __restrict__ x, const float* __restrict__ w,
    const float* __restrict__ wt, const float* __restrict__ x2g,
    const float* __restrict__ w2g, float* __restrict__ zout,
    float* __restrict__ zq) {
    __shared__ float rv[16][4];   // per-row per-wave winner value
    __shared__ int ri[16][4];     // per-row per-wave winner index
    __shared__ int widx[16];

    const int tid = threadIdx.x;
    const int wave = tid >> 6;
    const int lane = tid & 63;
    const int bm0 = blockIdx.x * 16;
    const int cbase = wave * 256 + lane * 4;   // this lane's 4 codes

    float acc[16][4];
#pragma unroll
    for (int r = 0; r < 16; ++r)
#pragma unroll
        for (int j = 0; j < 4; ++j) acc[r][j] = 0.f;

    const float* xp = x + (size_t)bm0 * DIM;   // uniform base
    const float* wtp = wt + cbase;

    for (int k4 = 0; k4 < DIM / 4; ++k4) {
        float4 wq[4];
#pragma unroll
        for (int kk = 0; kk < 4; ++kk)
            wq[kk] = *(const float4*)&wtp[(size_t)(k4 * 4 + kk) * K_CODES];
        float4 xq[16];
#pragma unroll
        for (int r = 0; r < 16; ++r)
            xq[r] = *(const float4*)&xp[r * DIM + k4 * 4];   // wave-uniform addr
#pragma unroll
        for (int kk = 0; kk < 4; ++kk) {
#pragma unroll
            for (int r = 0; r < 16; ++r) {
                float xv = ((const float*)&xq[r])[kk];
                acc[r][0] = __builtin_fmaf(xv, wq[kk].x, acc[r][0]);
                acc[r][1] = __builtin_fmaf(xv, wq[kk].y, acc[r][1]);
                acc[r][2] = __builtin_fmaf(xv, wq[kk].z, acc[r][2]);
                acc[r][3] = __builtin_fmaf(xv, wq[kk].w, acc[r][3]);
            }
        }
    }

    // fold to distances + per-lane argmin (j ascending, strict < = first wins)
    float4 w2v = *(const float4*)&w2g[cbase];
#pragma unroll
    for (int r = 0; r < 16; ++r) {
        float x2v = x2g[bm0 + r];  // uniform
        float bv = INFINITY;
        int bi = 0;
#pragma unroll
        for (int j = 0; j < 4; ++j) {
            float t = x2v - 2.0f * acc[r][j];
            float s = t + ((const float*)&w2v)[j];
            if (s < bv) { bv = s; bi = cbase + j; }
        }
        // wave-level butterfly reduce with (value, index) lexicographic min
#pragma unroll
        for (int m = 1; m < 64; m <<= 1) {
            float ov = __shfl_xor(bv, m);
            int oi = __shfl_xor(bi, m);
            if (ov < bv || (ov == bv && oi < bi)) { bv = ov; bi = oi; }
        }
        if (lane == 0) { rv[r][wave] = bv; ri[r][wave] = bi; }
    }
    __syncthreads();
    if (tid < 16) {
        float bv = rv[tid][0];
        int bi = ri[tid][0];
#pragma unroll
        for (int ww = 1; ww < 4; ++ww) {   // wave order ascending = code ascending
            float v = rv[tid][ww];
            int id = ri[tid][ww];
            if (v < bv || (v == bv && id < bi)) { bv = v; bi = id; }
        }
        widx[tid] = bi;
        zout[bm0 + tid] = (float)bi;
    }
    __syncthreads();
    // gather z_q: 16 rows x 64 float4, coalesced
    const float4* w4 = (const float4*)w;
    float4* zq4 = (float4*)zq;
#pragma unroll
    for (int p = 0; p < 4; ++p) {
        int lin = p * 256 + tid;
        int row = lin >> 6, q = lin & 63;
        zq4[(size_t)(bm0 + row) * 64 + q] = w4[(size_t)widx[row] * 64 + q];
    }
}

// ===========================================================================
// Fallback (round-5 passing kernel) if ws_size is too small for WT.
// ===========================================================================
#define BM 64
#define BN 128
#define BK 64
#define LDX 68

__global__ __launch_bounds__(256) void vq_kernel_lds(
    const float* __restrict__ x, const float* __restrict__ w,
    const float* __restrict__ x2g, const float* __restrict__ w2g,
    float* __restrict__ zout, float* __restrict__ zq) {
    __shared__ float xs[BM * LDX];
    __shared__ float ws_[BN * LDX];
    __shared__ float sw2[K_CODES];
    __shared__ float sx2[BM];
    __shared__ int widx[BM];

    const int tid = threadIdx.x;
    const int bm0 = blockIdx.x * BM;
    const int rg = tid & 15;
    const int cg = tid >> 4;

    for (int i = tid; i < K_CODES; i += 256) sw2[i] = w2g[i];
    if (tid < BM) sx2[tid] = x2g[bm0 + tid];

    float best[4];
    int bidx[4];
#pragma unroll
    for (int i = 0; i < 4; ++i) { best[i] = INFINITY; bidx[i] = 0; }

    const float4* x4 = (const float4*)x;
    const float4* w4 = (const float4*)w;

    for (int cn = 0; cn < K_CODES / BN; ++cn) {
        float acc[4][8];
#pragma unroll
        for (int i = 0; i < 4; ++i)
#pragma unroll
            for (int j = 0; j < 8; ++j) acc[i][j] = 0.f;

        for (int dk = 0; dk < DIM / BK; ++dk) {
            __syncthreads();
#pragma unroll
            for (int p = 0; p < 4; ++p) {
                int l = p * 256 + tid;
                int row = l >> 4, c4 = l & 15;
                float4 v = x4[(size_t)(bm0 + row) * (DIM / 4) + dk * (BK / 4) + c4];
                *(float4*)&xs[row * LDX + c4 * 4] = v;
            }
#pragma unroll
            for (int p = 0; p < 8; ++p) {
                int l = p * 256 + tid;
                int row = l >> 4, c4 = l & 15;
                float4 v = w4[(size_t)(cn * BN + row) * (DIM / 4) + dk * (BK / 4) + c4];
                *(float4*)&ws_[row * LDX + c4 * 4] = v;
            }
            __syncthreads();
#pragma unroll
            for (int d = 0; d < BK; d += 4) {
                float4 xv[4], wv[8];
#pragma unroll
                for (int i = 0; i < 4; ++i)
                    xv[i] = *(const float4*)&xs[(rg + 16 * i) * LDX + d];
#pragma unroll
                for (int j = 0; j < 8; ++j)
                    wv[j] = *(const float4*)&ws_[(cg + 16 * j) * LDX + d];
#pragma unroll
                for (int i = 0; i < 4; ++i)
#pragma unroll
                    for (int j = 0; j < 8; ++j) {
                        acc[i][j] = __builtin_fmaf(xv[i].x, wv[j].x, acc[i][j]);
                        acc[i][j] = __builtin_fmaf(xv[i].y, wv[j].y, acc[i][j]);
                        acc[i][j] = __builtin_fmaf(xv[i].z, wv[j].z, acc[i][j]);
                        acc[i][j] = __builtin_fmaf(xv[i].w, wv[j].w, acc[i][j]);
                    }
            }
        }
#pragma unroll
        for (int j = 0; j < 8; ++j) {
            int c = cn * BN + cg + 16 * j;
            float w2v = sw2[c];
#pragma unroll
            for (int i = 0; i < 4; ++i) {
                float t = sx2[rg + 16 * i] - 2.0f * acc[i][j];
                float s = t + w2v;
                if (s < best[i]) { best[i] = s; bidx[i] = c; }
            }
        }
    }

    __syncthreads();
    float* sval = xs;
    int* sidx = (int*)(xs + 64 * 17);
#pragma unroll
    for (int i = 0; i < 4; ++i) {
        sval[(rg + 16 * i) * 17 + cg] = best[i];
        sidx[(rg + 16 * i) * 17 + cg] = bidx[i];
    }
    __syncthreads();
    if (tid < BM) {
        float bv = INFINITY;
        int bi = 0;
        for (int c = 0; c < 16; ++c) {
            float v = sval[tid * 17 + c];
            int id = sidx[tid * 17 + c];
            if (v < bv || (v == bv && id < bi)) { bv = v; bi = id; }
        }
        widx[tid] = bi;
        zout[bm0 + tid] = (float)bi;
    }
    __syncthreads();
    float4* zq4 = (float4*)zq;
#pragma unroll
    for (int p = 0; p < 16; ++p) {
        int lin = p * 256 + tid;
        int row = lin >> 6, q = lin & 63;
        zq4[(size_t)(bm0 + row) * 64 + q] = w4[(size_t)widx[row] * 64 + q];
    }
}

extern "C" void kernel_launch(void* const* d_in, const int* in_sizes, int n_in,
                              void* d_out, int out_size, void* d_ws, size_t ws_size,
                              hipStream_t stream) {
    const float* z_e = (const float*)d_in[0];
    const float* emb = (const float*)d_in[1];
    float* x2g = (float*)d_ws;                   // [32768]
    float* w2g = x2g + N_ROWS;                   // [1024]
    float* wtg = w2g + K_CODES;                  // [256*1024]
    float* zout = (float*)d_out;
    float* zq = (float*)d_out + N_ROWS;

    npsumsq_kernel<<<N_ROWS / 16, 64, 0, stream>>>(z_e, x2g);
    npsumsq_kernel<<<K_CODES / 16, 64, 0, stream>>>(emb, w2g);

    if (ws_size >= WS_NEEDED) {
        transpose_kernel<<<dim3(K_CODES / 64, DIM / 64), 256, 0, stream>>>(emb, wtg);
        vq_main<<<N_ROWS / 16, 256, 0, stream>>>(z_e, emb, wtg, x2g, w2g, zout, zq);
    } else {
        vq_kernel_lds<<<N_ROWS / BM, 256, 0, stream>>>(z_e, emb, x2g, w2g, zout, zq);
    }
}